// Round 6
// baseline (250.604 us; speedup 1.0000x reference)
//
#include <hip/hip_runtime.h>
#include <math.h>

// Problem constants
#define NRAYS        32768
#define MARCH_ITERS  64
#define EPS_         1e-4f
#define STEP_        ((1.0f + 1.0f/64.0f) / 64.0f)   // exact in fp32

typedef __attribute__((ext_vector_type(8)))  short    short8;   // 8 bf16
typedef __attribute__((ext_vector_type(4)))  float    float4v;  // C/D frag
typedef __attribute__((ext_vector_type(4)))  unsigned uint4v;

__device__ __forceinline__ short8 mk_frag(unsigned p0, unsigned p1,
                                          unsigned p2, unsigned p3) {
    uint4v v = {p0, p1, p2, p3};
    return __builtin_bit_cast(short8, v);
}

// One v_perm_b32: low16 = trunc-bf16(a), high16 = trunc-bf16(b).
__device__ __forceinline__ unsigned packbf(unsigned a, unsigned b) {
    return __builtin_amdgcn_perm(b, a, 0x07060302u);
}

// Exact 3-way truncation split: x == hi + mid + lo bit-exactly in fp32.
struct Split3 { unsigned h, m, l; };
__device__ __forceinline__ Split3 split3(float x) {
    unsigned xu = __float_as_uint(x);
    float xh = __uint_as_float(xu & 0xFFFF0000u);
    float r  = x - xh;                        // exact
    unsigned ru = __float_as_uint(r);
    float xm = __uint_as_float(ru & 0xFFFF0000u);
    float r2 = r - xm;                        // exact, fits bf16
    return { xu, ru, __float_as_uint(r2) };
}

// Transposed pipeline, one wave = 16 rays (ray = col everywhere).
// mfma_f32_16x16x32_bf16 layouts (verified):
//   A[row=lane&15][k=(lane>>4)*8+j]   B[k=(lane>>4)*8+j][col=lane&15]
//   C/D: col=lane&15, row=(lane>>4)*4+reg
// L1 hidden assignment H(t,q,r) = 32*(t>>1) + 8q + 4*(t&1) + r  makes the
// C1->B2 handoff PURELY IN-LANE: lane (q,m)'s C1 rows are exactly the
// k-slots (k = 32h+8q+j) its own L2 B-fragment needs. No cross-lane ops
// between layers; only 2 cross-quad shuffles at the very end (L3).
__global__ __launch_bounds__(256, 2) void sdf_tr2_k(
    const float* __restrict__ rays,
    const float* __restrict__ W0,  const float* __restrict__ b0,
    const float* __restrict__ W1,  const float* __restrict__ b1,
    const float* __restrict__ W2,  const float* __restrict__ b2,
    const float* __restrict__ Wr0, const float* __restrict__ br0,
    const float* __restrict__ Wr1, const float* __restrict__ br1,
    float* __restrict__ out)
{
    const int lane   = threadIdx.x & 63;
    const int waveId = threadIdx.x >> 6;
    const int quad   = lane >> 4;
    const int m      = lane & 15;
    const int kind   = blockIdx.x & 1;                 // 0=march, 1=tput
    const int rayBase = ((blockIdx.x >> 1) * 4 + waveId) * 16;

    // ---- per-lane ray (ray = rayBase + m, replicated over quads) ----
    const float* rp = rays + (rayBase + m) * 6;
    const float ox = rp[0], oy = rp[1], oz = rp[2];
    const float dx = rp[3], dy = rp[4], dz = rp[5];

    // ---- A1: W0^T splits + b0 splits in A-layout, 21 K-slots (16 VGPRs) ----
    // K-slots: x:0-5  y:6-11  z:12-17  bias:18-20  zero:21-31
    // A side per coord: Wh,Wm,Wl,Wh,Wm,Wh ; B side: ph,ph,ph,pm,pm,pl
    // Row j of tile t = H(t, m>>2, m&3) (see header comment).
    short8 A1[4];
    #pragma unroll
    for (int t = 0; t < 4; ++t) {
        int j = 32 * (t >> 1) + 8 * (m >> 2) + 4 * (t & 1) + (m & 3);
        Split3 wx = split3(W0[j]);
        Split3 wy = split3(W0[64 + j]);
        Split3 wz = split3(W0[128 + j]);
        Split3 bb = split3(b0[j]);
        unsigned a0, a1, a2, a3;
        if      (quad == 0) { a0 = packbf(wx.h, wx.m); a1 = packbf(wx.l, wx.h);
                              a2 = packbf(wx.m, wx.h); a3 = packbf(wy.h, wy.m); }
        else if (quad == 1) { a0 = packbf(wy.l, wy.h); a1 = packbf(wy.m, wy.h);
                              a2 = packbf(wz.h, wz.m); a3 = packbf(wz.l, wz.h); }
        else if (quad == 2) { a0 = packbf(wz.m, wz.h); a1 = packbf(bb.h, bb.m);
                              a2 = packbf(bb.l, 0u);   a3 = 0u; }
        else                { a0 = a1 = a2 = a3 = 0u; }
        A1[t] = mk_frag(a0, a1, a2, a3);
    }

    // ---- A2: W1^T 3-split in A-layout (24 frags = 96 VGPRs) ----
    // A2[s][h][t]: row j2 = 16t+m, k = 32h + 8*quad + jj (R3-verified indexing)
    short8 A2[3][2][4];
    #pragma unroll
    for (int h = 0; h < 2; ++h)
        #pragma unroll
        for (int t = 0; t < 4; ++t) {
            unsigned ph[4], pm[4], pl[4];
            #pragma unroll
            for (int jp = 0; jp < 4; ++jp) {
                int k0 = 32 * h + quad * 8 + 2 * jp;
                int j2 = 16 * t + m;
                Split3 a = split3(W1[k0 * 64 + j2]);
                Split3 b = split3(W1[(k0 + 1) * 64 + j2]);
                ph[jp] = packbf(a.h, b.h);
                pm[jp] = packbf(a.m, b.m);
                pl[jp] = packbf(a.l, b.l);
            }
            A2[0][h][t] = mk_frag(ph[0], ph[1], ph[2], ph[3]);
            A2[1][h][t] = mk_frag(pm[0], pm[1], pm[2], pm[3]);
            A2[2][h][t] = mk_frag(pl[0], pl[1], pl[2], pl[3]);
        }

    // ---- b1 (folded into C2 init) and W2, per-lane rows j2 = 16t+4q+r ----
    float4v b1v[4], w2v[4];
    #pragma unroll
    for (int t = 0; t < 4; ++t) {
        int base = 16 * t + 4 * quad;
        b1v[t] = (float4v){b1[base], b1[base + 1], b1[base + 2], b1[base + 3]};
        w2v[t] = (float4v){W2[base], W2[base + 1], W2[base + 2], W2[base + 3]};
    }
    const float b2s = b2[0];

    // L2 product order (sW = W1 split, sH = h0 split), small terms first:
    // (m,m)(l,h)(h,l)(m,h)(h,m)(h,h)
    const int pw_[6] = {1, 2, 0, 1, 0, 0};
    const int ph_[6] = {1, 0, 2, 0, 1, 0};

    // ---- whole-wave SDF eval; returns d for ray m in EVERY lane ----
    auto evalSDF = [&](float px, float py, float pz) -> float {
        // B1: position splits in B-layout K-slots (~25 VALU)
        Split3 sx = split3(px), sy = split3(py), sz = split3(pz);
        unsigned d0, d1, d2, d3;
        if      (quad == 0) { d0 = packbf(sx.h, sx.h); d1 = packbf(sx.h, sx.m);
                              d2 = packbf(sx.m, sx.l); d3 = packbf(sy.h, sy.h); }
        else if (quad == 1) { d0 = packbf(sy.h, sy.m); d1 = packbf(sy.m, sy.l);
                              d2 = packbf(sz.h, sz.h); d3 = packbf(sz.h, sz.m); }
        else if (quad == 2) { d0 = packbf(sz.m, sz.l); d1 = 0x3F803F80u;
                              d2 = 0x00003F80u;        d3 = 0u; }
        else                { d0 = d1 = d2 = d3 = 0u; }
        short8 B1 = mk_frag(d0, d1, d2, d3);

        // L1: 4 independent MFMAs -> C1[t][r] = h0[32*(t>>1)+8q+4*(t&1)+r]
        const float4v z4 = {0.f, 0.f, 0.f, 0.f};
        float4v C1[4];
        #pragma unroll
        for (int t = 0; t < 4; ++t)
            C1[t] = __builtin_amdgcn_mfma_f32_16x16x32_bf16(A1[t], B1, z4, 0, 0, 0);

        // relu + exact split + in-lane pack: P[s][t] = pairs (r0,r1),(r2,r3)
        unsigned P[3][4][2];
        #pragma unroll
        for (int t = 0; t < 4; ++t) {
            Split3 s0 = split3(fmaxf(C1[t][0], 0.f));
            Split3 s1 = split3(fmaxf(C1[t][1], 0.f));
            Split3 s2 = split3(fmaxf(C1[t][2], 0.f));
            Split3 s3 = split3(fmaxf(C1[t][3], 0.f));
            P[0][t][0] = packbf(s0.h, s1.h); P[0][t][1] = packbf(s2.h, s3.h);
            P[1][t][0] = packbf(s0.m, s1.m); P[1][t][1] = packbf(s2.m, s3.m);
            P[2][t][0] = packbf(s0.l, s1.l); P[2][t][1] = packbf(s2.l, s3.l);
        }

        // B2 assembly: PURELY IN-LANE register renaming (no cross-lane ops):
        // B2[s][h] k-slots (32h+8q+0..7) = tiles (2h, 2h+1) rows 4q..4q+3.
        short8 B2[3][2];
        #pragma unroll
        for (int s = 0; s < 3; ++s)
            #pragma unroll
            for (int h = 0; h < 2; ++h)
                B2[s][h] = mk_frag(P[s][2 * h][0],     P[s][2 * h][1],
                                   P[s][2 * h + 1][0], P[s][2 * h + 1][1]);

        // L2: C2[j2][ray], b1 folded into init; 48 MFMAs, 4 indep chains
        float4v C2[4];
        #pragma unroll
        for (int t = 0; t < 4; ++t) C2[t] = b1v[t];
        #pragma unroll
        for (int p = 0; p < 6; ++p)
            #pragma unroll
            for (int h = 0; h < 2; ++h)
                #pragma unroll
                for (int t = 0; t < 4; ++t)
                    C2[t] = __builtin_amdgcn_mfma_f32_16x16x32_bf16(
                        A2[pw_[p]][h][t], B2[ph_[p]][h], C2[t], 0, 0, 0);

        // L3: in-lane relu*W2 (4 parallel chains), then 2 cross-quad shuffles
        float q0 = 0.f, q1 = 0.f, q2 = 0.f, q3 = 0.f;
        #pragma unroll
        for (int t = 0; t < 4; ++t) {
            q0 = fmaf(fmaxf(C2[t][0], 0.f), w2v[t][0], q0);
            q1 = fmaf(fmaxf(C2[t][1], 0.f), w2v[t][1], q1);
            q2 = fmaf(fmaxf(C2[t][2], 0.f), w2v[t][2], q2);
            q3 = fmaf(fmaxf(C2[t][3], 0.f), w2v[t][3], q3);
        }
        float part = (q0 + q1) + (q2 + q3);
        part += __shfl_xor(part, 16, 64);
        part += __shfl_xor(part, 32, 64);
        return b2s + part;                       // d at every lane
    };

    if (kind == 0) {
        // ---- sphere march: 64 sequential evals ----
        bool  hit = false;
        float cd  = 0.f;
        #pragma unroll 1
        for (int it = 0; it < MARCH_ITERS; ++it) {
            float d = evalSDF(fmaf(dx, cd, ox), fmaf(dy, cd, oy), fmaf(dz, cd, oz));
            bool c = (d < EPS_) && (cd >= 0.f) && (cd <= 1.f);
            hit = hit || c;
            if (!hit) cd += d;
            if (__all(hit)) break;               // all 16 rays frozen
        }

        // ---- reflection net: quad q handles hidden j in [16q, 16q+16) ----
        const float px = fmaf(dx, cd, ox), py = fmaf(dy, cd, oy), pz = fmaf(dz, cd, oz);
        float r0 = 0.f, r1 = 0.f, r2 = 0.f;
        #pragma unroll 4
        for (int jj = 0; jj < 16; ++jj) {
            int j = quad * 16 + jj;
            float a = fmaf(px, Wr0[j],
                      fmaf(py, Wr0[64 + j],
                      fmaf(pz, Wr0[128 + j],
                      fmaf(dx, Wr0[192 + j],
                      fmaf(dy, Wr0[256 + j],
                      fmaf(dz, Wr0[320 + j], br0[j]))))));
            a = fmaxf(a, 0.f);
            r0 = fmaf(a, Wr1[j * 3 + 0], r0);
            r1 = fmaf(a, Wr1[j * 3 + 1], r1);
            r2 = fmaf(a, Wr1[j * 3 + 2], r2);
        }
        r0 += __shfl_xor(r0, 16, 64); r0 += __shfl_xor(r0, 32, 64);
        r1 += __shfl_xor(r1, 16, 64); r1 += __shfl_xor(r1, 32, 64);
        r2 += __shfl_xor(r2, 16, 64); r2 += __shfl_xor(r2, 32, 64);
        r0 = 1.f / (1.f + expf(-(r0 + br1[0])));
        r1 = 1.f / (1.f + expf(-(r1 + br1[1])));
        r2 = 1.f / (1.f + expf(-(r2 + br1[2])));
        if (!hit) { r0 = 0.f; r1 = 0.f; r2 = 0.f; }
        if (lane < 16) {
            float* op = out + (rayBase + lane) * 4;
            op[0] = r0; op[1] = r1; op[2] = r2;
        }
    } else {
        // ---- tput scan: 65 independent evals; tput == running min (validated) ----
        float cm = evalSDF(ox, oy, oz);
        #pragma unroll 1
        for (int i = 1; i <= 64; ++i) {
            float t_i = STEP_ * (float)i;
            cm = fminf(cm, evalSDF(fmaf(dx, t_i, ox), fmaf(dy, t_i, oy), fmaf(dz, t_i, oz)));
        }
        if (lane < 16)
            out[(rayBase + lane) * 4 + 3] = cm;
    }
}

extern "C" void kernel_launch(void* const* d_in, const int* in_sizes, int n_in,
                              void* d_out, int out_size, void* d_ws, size_t ws_size,
                              hipStream_t stream) {
    const float* rays = (const float*)d_in[0];
    const float* W0   = (const float*)d_in[1];
    const float* b0   = (const float*)d_in[2];
    const float* W1   = (const float*)d_in[3];
    const float* b1   = (const float*)d_in[4];
    const float* W2   = (const float*)d_in[5];
    const float* b2   = (const float*)d_in[6];
    const float* Wr0  = (const float*)d_in[7];
    const float* br0  = (const float*)d_in[8];
    const float* Wr1  = (const float*)d_in[9];
    const float* br1  = (const float*)d_in[10];
    float* out = (float*)d_out;

    // 1024 blocks x 4 waves = 4096 waves: even blocks march (out.xyz),
    // odd blocks tput (out.w); 16 rays per wave.
    hipLaunchKernelGGL(sdf_tr2_k, dim3(NRAYS / 16 / 2), dim3(256), 0, stream,
                       rays, W0, b0, W1, b1, W2, b2, Wr0, br0, Wr1, br1, out);
}